// Round 5
// baseline (567.241 us; speedup 1.0000x reference)
//
#include <hip/hip_runtime.h>

#define B_  4
#define S_  2048
#define D_  1024
#define H_  16
#define DK_ 64

typedef unsigned short ushort;
typedef __attribute__((ext_vector_type(8))) short short8;
typedef __attribute__((ext_vector_type(8))) unsigned short ushort8;
typedef __attribute__((ext_vector_type(4))) float f32x4;

// scores use exp2: fold 0.125 * log2(e) into Q at projection time
#define QSCALE 0.18033688011112042f

__device__ __forceinline__ ushort f2bf(float f) {  // RNE
    unsigned int u = __float_as_uint(f);
    u += 0x7fffu + ((u >> 16) & 1u);
    return (ushort)(u >> 16);
}
__device__ __forceinline__ ushort f2bf_hu(float f) {  // round-half-up, f >= 0
    return (ushort)((__float_as_uint(f) + 0x8000u) >> 16);
}

__device__ __forceinline__ void gl_lds16(const ushort* g, ushort* ldsbase) {
    __builtin_amdgcn_global_load_lds(
        (const __attribute__((address_space(1))) void*)g,
        (__attribute__((address_space(3))) void*)ldsbase, 16, 0, 0);
}

// ---------------------------------------------------------------------------
// Cast q,k,v + Wq,Wk,Wv,Wo to bf16 in one launch.
// ---------------------------------------------------------------------------
__global__ __launch_bounds__(256) void cast_all(
    const float* __restrict__ q, const float* __restrict__ k,
    const float* __restrict__ v, const float* __restrict__ Wq,
    const float* __restrict__ Wk, const float* __restrict__ Wv,
    const float* __restrict__ Wo, ushort* __restrict__ qkv_dst,
    ushort* __restrict__ w_dst) {
    const int bid = blockIdx.x;
    const float* src;
    ushort* dst;
    int lb;
    if (bid < 12288) {
        const int s = bid >> 12;
        lb = bid & 4095;
        src = (s == 0) ? q : (s == 1) ? k : v;
        dst = qkv_dst + (size_t)s * (B_ * S_ * D_);
    } else {
        const int wi = (bid - 12288) >> 9;
        lb = (bid - 12288) & 511;
        src = (wi == 0) ? Wq : (wi == 1) ? Wk : (wi == 2) ? Wv : Wo;
        dst = w_dst + (size_t)wi * (D_ * D_);
    }
    const int i = lb * 2048 + threadIdx.x * 8;
    const float4 a = *(const float4*)(src + i);
    const float4 b = *(const float4*)(src + i + 4);
    ushort8 r;
    r[0] = f2bf(a.x); r[1] = f2bf(a.y); r[2] = f2bf(a.z); r[3] = f2bf(a.w);
    r[4] = f2bf(b.x); r[5] = f2bf(b.y); r[6] = f2bf(b.z); r[7] = f2bf(b.w);
    *(ushort8*)(dst + i) = r;
}

// ---------------------------------------------------------------------------
// int32 mask -> 1 bit per element (bit i of word = k position). 2 MB total.
// ---------------------------------------------------------------------------
__global__ __launch_bounds__(256) void mask_bits_kernel(
    const int* __restrict__ m, unsigned long long* __restrict__ bits) {
    const size_t idx = (size_t)blockIdx.x * 256 + threadIdx.x;
    const unsigned long long bal = __ballot(m[idx] != 0);
    if ((threadIdx.x & 63) == 0) bits[idx >> 6] = bal;
}

// ---------------------------------------------------------------------------
// Fused Q/K/V projection (blockIdx.z selects). out = (A @ W^T + b)*scale,
// bf16 scatter to [B,H,S,DK] (uniform, coalesced 32B runs).
// ---------------------------------------------------------------------------
__global__ __launch_bounds__(256) void gemm_proj(
    const ushort* __restrict__ qb, const ushort* __restrict__ kb,
    const ushort* __restrict__ vb, const ushort* __restrict__ Wb,
    const float* __restrict__ bq, const float* __restrict__ bk,
    const float* __restrict__ bv, ushort* __restrict__ Qd,
    ushort* __restrict__ Kd, ushort* __restrict__ Vd) {
    const int z = blockIdx.z;
    const ushort* A  = (z == 0) ? qb : (z == 1) ? kb : vb;
    const ushort* Wm = Wb + (size_t)z * (D_ * D_);
    const float* bias = (z == 0) ? bq : (z == 1) ? bk : bv;
    ushort* outp = (z == 0) ? Qd : (z == 1) ? Kd : Vd;
    const float scale = (z == 0) ? QSCALE : 1.0f;

    __shared__ ushort As[128 * 32];
    __shared__ ushort Bs[128 * 32];
    const int t = threadIdx.x, w = t >> 6, lane = t & 63;
    const int ln15 = lane & 15, quad = lane >> 4;
    const int wr = w >> 1, wc = w & 1;
    const int n0 = blockIdx.x * 128, m0 = blockIdx.y * 128;
    const int srow = lane >> 2;
    const int sg = (lane & 3) * 8;

    f32x4 acc[4][4] = {};
    for (int k0 = 0; k0 < D_; k0 += 32) {
#pragma unroll
        for (int c = 0; c < 2; ++c) {
            const int cc = w * 2 + c;
            const int row = cc * 16 + srow;
            gl_lds16(A + (size_t)(m0 + row) * D_ + k0 + sg, As + cc * 512);
            gl_lds16(Wm + (size_t)(n0 + row) * D_ + k0 + sg, Bs + cc * 512);
        }
        __syncthreads();
        short8 af[4], bf[4];
#pragma unroll
        for (int i = 0; i < 4; ++i) {
            af[i] = *(const short8*)(As + (wr * 64 + i * 16 + ln15) * 32 + quad * 8);
            bf[i] = *(const short8*)(Bs + (wc * 64 + i * 16 + ln15) * 32 + quad * 8);
        }
#pragma unroll
        for (int mt = 0; mt < 4; ++mt)
#pragma unroll
            for (int nt = 0; nt < 4; ++nt)
                acc[mt][nt] = __builtin_amdgcn_mfma_f32_16x16x32_bf16(
                    af[mt], bf[nt], acc[mt][nt], 0, 0, 0);
        __syncthreads();
    }
#pragma unroll
    for (int mt = 0; mt < 4; ++mt) {
#pragma unroll
        for (int r = 0; r < 4; ++r) {
            const int row = m0 + wr * 64 + mt * 16 + quad * 4 + r;
            const int bb = row >> 11, s = row & (S_ - 1);
#pragma unroll
            for (int nt = 0; nt < 4; ++nt) {
                const int col = n0 + wc * 64 + nt * 16 + ln15;
                const float vv = (acc[mt][nt][r] + bias[col]) * scale;
                const int h = col >> 6, dk = col & 63;
                outp[((((size_t)bb * H_ + h) * S_ + s) << 6) + dk] = f2bf(vv);
            }
        }
    }
}

// ---------------------------------------------------------------------------
// V [bh][s][dk] -> V^T [bh][dk][s], LDS tile transpose (coalesced both sides)
// ---------------------------------------------------------------------------
__global__ __launch_bounds__(256) void vtrans(const ushort* __restrict__ Vs_,
                                              ushort* __restrict__ Vt_) {
    __shared__ ushort L[64 * 76];  // stride 76: spreads the gather reads
    const int t = threadIdx.x;
    const int bh = blockIdx.y;
    const int s0 = blockIdx.x * 64;
    const ushort* src = Vs_ + (size_t)bh * S_ * DK_;
    ushort* dst = Vt_ + (size_t)bh * DK_ * S_;
    const int r = t >> 2, g = t & 3;
#pragma unroll
    for (int gg = 0; gg < 2; ++gg) {
        const int grp = g + gg * 4;
        const ushort8 v = *(const ushort8*)(src + (size_t)(s0 + r) * DK_ + grp * 8);
        *(ushort8*)(&L[r * 76 + grp * 8]) = v;
    }
    __syncthreads();
    const int dim = t >> 2;
#pragma unroll
    for (int gg = 0; gg < 2; ++gg) {
        const int sg = g + gg * 4;
        ushort8 o;
#pragma unroll
        for (int j = 0; j < 8; ++j) o[j] = L[(sg * 8 + j) * 76 + dim];
        *(ushort8*)(dst + (size_t)dim * S_ + s0 + sg * 8) = o;
    }
}

// ---------------------------------------------------------------------------
// Output projection: fp32 out = A @ W^T + b, flat [M,D]
// ---------------------------------------------------------------------------
__global__ __launch_bounds__(256) void gemm_out(const ushort* __restrict__ A,
                                                const ushort* __restrict__ Wm,
                                                const float* __restrict__ bias,
                                                float* __restrict__ out) {
    __shared__ ushort As[128 * 32];
    __shared__ ushort Bs[128 * 32];
    const int t = threadIdx.x, w = t >> 6, lane = t & 63;
    const int ln15 = lane & 15, quad = lane >> 4;
    const int wr = w >> 1, wc = w & 1;
    const int n0 = blockIdx.x * 128, m0 = blockIdx.y * 128;
    const int srow = lane >> 2;
    const int sg = (lane & 3) * 8;

    f32x4 acc[4][4] = {};
    for (int k0 = 0; k0 < D_; k0 += 32) {
#pragma unroll
        for (int c = 0; c < 2; ++c) {
            const int cc = w * 2 + c;
            const int row = cc * 16 + srow;
            gl_lds16(A + (size_t)(m0 + row) * D_ + k0 + sg, As + cc * 512);
            gl_lds16(Wm + (size_t)(n0 + row) * D_ + k0 + sg, Bs + cc * 512);
        }
        __syncthreads();
        short8 af[4], bf[4];
#pragma unroll
        for (int i = 0; i < 4; ++i) {
            af[i] = *(const short8*)(As + (wr * 64 + i * 16 + ln15) * 32 + quad * 8);
            bf[i] = *(const short8*)(Bs + (wc * 64 + i * 16 + ln15) * 32 + quad * 8);
        }
#pragma unroll
        for (int mt = 0; mt < 4; ++mt)
#pragma unroll
            for (int nt = 0; nt < 4; ++nt)
                acc[mt][nt] = __builtin_amdgcn_mfma_f32_16x16x32_bf16(
                    af[mt], bf[nt], acc[mt][nt], 0, 0, 0);
        __syncthreads();
    }
#pragma unroll
    for (int mt = 0; mt < 4; ++mt) {
#pragma unroll
        for (int r = 0; r < 4; ++r) {
            const int row = m0 + wr * 64 + mt * 16 + quad * 4 + r;
#pragma unroll
            for (int nt = 0; nt < 4; ++nt) {
                const int col = n0 + wc * 64 + nt * 16 + ln15;
                out[(size_t)row * D_ + col] = acc[mt][nt][r] + bias[col];
            }
        }
    }
}

// ---------------------------------------------------------------------------
// Flash attention. LDS = Ks dbuf (16K) + Ps (18K) = 34K -> 3+ blocks/CU.
// Q frags in registers (loaded once). V^T frags loaded global->reg per tile
// (L1/L2-hot, issued at tile start so QK+softmax hides the latency).
// One barrier per tile; K staged async one tile ahead; mask bits prefetched.
// ---------------------------------------------------------------------------
__global__ __launch_bounds__(256, 3) void attn_mfma(
    const ushort* __restrict__ Qd, const ushort* __restrict__ Kd,
    const ushort* __restrict__ Vtg, const unsigned long long* __restrict__ bits,
    ushort* __restrict__ ctx) {
    __shared__ ushort Ks[2][64 * 64];  // [key][dk] swizzled groups, 2 x 8 KB
    __shared__ ushort Ps[128 * 72];    // [q][key] A-layout, padded, 18 KB

    const int t = threadIdx.x, w = t >> 6, lane = t & 63;
    const int ln15 = lane & 15, quad = lane >> 4;
    const int lp = lane & 7, lr8 = lane >> 3;
    const int bh = blockIdx.y, b = bh >> 4, h = bh & 15;
    const int q0 = blockIdx.x * 128;

    const ushort* Qb = Qd + (size_t)bh * (S_ * DK_);
    const ushort* Kb = Kd + (size_t)bh * (S_ * DK_);
    const ushort* Vb = Vtg + (size_t)bh * (DK_ * S_);  // [dk][s]
    const unsigned long long* mbits = bits + (size_t)b * S_ * (S_ / 64);

    int moff[2][4];
#pragma unroll
    for (int mt = 0; mt < 2; ++mt)
#pragma unroll
        for (int r = 0; r < 4; ++r)
            moff[mt][r] = (q0 + w * 32 + mt * 16 + quad * 4 + r) * (S_ / 64);

    // Q fragments: loaded once, live in registers all kernel
    short8 aq[2][2];  // [ks][mt]
#pragma unroll
    for (int ks = 0; ks < 2; ++ks)
#pragma unroll
        for (int mt = 0; mt < 2; ++mt)
            aq[ks][mt] = *(const short8*)(
                Qb + (size_t)(q0 + w * 32 + mt * 16 + ln15) * DK_ + ks * 32 + quad * 8);

    auto stageK = [&](int kt, int p) {
        const int k0 = kt * 64;
#pragma unroll
        for (int c = 0; c < 2; ++c) {
            const int cc = w * 2 + c;
            const int krow = cc * 8 + lr8;
            gl_lds16(Kb + (size_t)(k0 + krow) * DK_ + (lp ^ lr8) * 8, &Ks[p][cc * 512]);
        }
    };

    stageK(0, 0);
    unsigned long long mw[2][4];
#pragma unroll
    for (int mt = 0; mt < 2; ++mt)
#pragma unroll
        for (int r = 0; r < 4; ++r) mw[mt][r] = mbits[moff[mt][r]];

    f32x4 O[2][4] = {};
    f32x4 lsum[2] = {};
    short8 vone;
#pragma unroll
    for (int j = 0; j < 8; ++j) vone[j] = (short)0x3F80;  // bf16(1.0)

    int p = 0;
    for (int kt = 0; kt < S_ / 64; ++kt) {
        __syncthreads();  // drains stageK(kt); buffer p^1 now free
        if (kt < S_ / 64 - 1) stageK(kt + 1, p ^ 1);

        // V^T fragments for THIS tile: global->reg, latency hidden by QK+softmax
        short8 bv[2][4];
#pragma unroll
        for (int ks = 0; ks < 2; ++ks)
#pragma unroll
            for (int nt = 0; nt < 4; ++nt)
                bv[ks][nt] = *(const short8*)(
                    Vb + (size_t)(nt * 16 + ln15) * S_ + kt * 64 + ks * 32 + quad * 8);

        // ---- S' = (Q*QSCALE) K^T
        f32x4 sc[2][4] = {};
#pragma unroll
        for (int ks = 0; ks < 2; ++ks) {
            short8 bk[4];
#pragma unroll
            for (int nt = 0; nt < 4; ++nt) {
                const int row = nt * 16 + ln15;
                bk[nt] = *(const short8*)(&Ks[p][row * 64 + ((ks * 4 + quad) ^ (row & 7)) * 8]);
            }
#pragma unroll
            for (int mt = 0; mt < 2; ++mt)
#pragma unroll
                for (int nt = 0; nt < 4; ++nt)
                    sc[mt][nt] = __builtin_amdgcn_mfma_f32_16x16x32_bf16(
                        aq[ks][mt], bk[nt], sc[mt][nt], 0, 0, 0);
        }

        // ---- P = maskbit ? exp2(S') : 0, to LDS in A-operand layout
#pragma unroll
        for (int mt = 0; mt < 2; ++mt) {
#pragma unroll
            for (int r = 0; r < 4; ++r) {
                const int prow = w * 32 + mt * 16 + quad * 4 + r;
                const unsigned long long mword = mw[mt][r];
#pragma unroll
                for (int nt = 0; nt < 4; ++nt) {
                    float pv = __builtin_amdgcn_exp2f(sc[mt][nt][r]);
                    pv = ((mword >> (ln15 + nt * 16)) & 1ull) ? pv : 0.0f;
                    Ps[prow * 72 + nt * 16 + ln15] = f2bf_hu(pv);
                }
            }
        }
        // prefetch mask for kt+1
        if (kt < S_ / 64 - 1) {
#pragma unroll
            for (int mt = 0; mt < 2; ++mt)
#pragma unroll
                for (int r = 0; r < 4; ++r)
                    mw[mt][r] = mbits[moff[mt][r] + kt + 1];
        }
        // Ps rows are wave-private; in-wave lgkmcnt ordering suffices

        // ---- O += P V^T ; lsum += P @ ones
#pragma unroll
        for (int ks = 0; ks < 2; ++ks) {
            short8 ap[2];
#pragma unroll
            for (int mt = 0; mt < 2; ++mt)
                ap[mt] = *(const short8*)(Ps + (w * 32 + mt * 16 + ln15) * 72 + ks * 32 + quad * 8);
#pragma unroll
            for (int mt = 0; mt < 2; ++mt) {
#pragma unroll
                for (int nt = 0; nt < 4; ++nt)
                    O[mt][nt] = __builtin_amdgcn_mfma_f32_16x16x32_bf16(
                        ap[mt], bv[ks][nt], O[mt][nt], 0, 0, 0);
                lsum[mt] = __builtin_amdgcn_mfma_f32_16x16x32_bf16(
                    ap[mt], vone, lsum[mt], 0, 0, 0);
            }
        }
        p ^= 1;
    }

    // finalize: ctx[b][s][h*64+dim] = O / lsum (bf16, feeds out-proj)
#pragma unroll
    for (int mt = 0; mt < 2; ++mt) {
#pragma unroll
        for (int r = 0; r < 4; ++r) {
            const int qg = q0 + w * 32 + mt * 16 + quad * 4 + r;
            const float inv = __builtin_amdgcn_rcpf(lsum[mt][r]);
#pragma unroll
            for (int nt = 0; nt < 4; ++nt) {
                const int dim = nt * 16 + ln15;
                ctx[((size_t)b * S_ + qg) * D_ + h * DK_ + dim] = f2bf(O[mt][nt][r] * inv);
            }
        }
    }
}

// ---------------------------------------------------------------------------
extern "C" void kernel_launch(void* const* d_in, const int* in_sizes, int n_in,
                              void* d_out, int out_size, void* d_ws, size_t ws_size,
                              hipStream_t stream) {
    (void)in_sizes; (void)n_in; (void)out_size; (void)ws_size;
    const float* query = (const float*)d_in[0];
    const float* key_  = (const float*)d_in[1];
    const float* value = (const float*)d_in[2];
    const int*   mask  = (const int*)d_in[3];
    const float* Wq = (const float*)d_in[4];
    const float* bq = (const float*)d_in[5];
    const float* Wk = (const float*)d_in[6];
    const float* bk = (const float*)d_in[7];
    const float* Wv = (const float*)d_in[8];
    const float* bv = (const float*)d_in[9];
    const float* Wo = (const float*)d_in[10];
    const float* bo = (const float*)d_in[11];
    float* out = (float*)d_out;

    const size_t nX = (size_t)B_ * S_ * D_;  // 8,388,608
    const size_t nW = (size_t)D_ * D_;       // 1,048,576
    ushort* qkv = (ushort*)d_ws;       // 3*nX bf16 (q,k,v casts)
    ushort* Wb  = qkv + 3 * nX;        // 4*nW bf16
    ushort* Qd  = Wb + 4 * nW;
    ushort* Kd  = Qd + nX;
    ushort* Vd  = Kd + nX;             // standard [B,H,S,DK]
    unsigned long long* bits = (unsigned long long*)(Vd + nX);  // 2 MB
    ushort* ctx = qkv;                 // q-cast region, dead after gemm_proj
    ushort* VtT = qkv + 2 * nX;        // v-cast region, dead after gemm_proj

    cast_all<<<14336, 256, 0, stream>>>(query, key_, value, Wq, Wk, Wv, Wo, qkv, Wb);
    mask_bits_kernel<<<B_ * S_ * S_ / 256, 256, 0, stream>>>(mask, bits);

    dim3 gp(D_ / 128, (B_ * S_) / 128, 3);  // (8, 64, 3)
    gemm_proj<<<gp, 256, 0, stream>>>(qkv, qkv + nX, qkv + 2 * nX, Wb,
                                      bq, bk, bv, Qd, Kd, Vd);

    dim3 gv(S_ / 64, B_ * H_);  // (32, 64)
    vtrans<<<gv, 256, 0, stream>>>(Vd, VtT);

    dim3 ga(S_ / 128, B_ * H_);  // (16, 64)
    attn_mfma<<<ga, 256, 0, stream>>>(Qd, Kd, VtT, bits, ctx);

    dim3 go(D_ / 128, (B_ * S_) / 128);  // (8, 64)
    gemm_out<<<go, 256, 0, stream>>>(ctx, Wb + 3 * nW, bo, out);
}

// Round 6
// 470.056 us; speedup vs baseline: 1.2068x; 1.2068x over previous
//
#include <hip/hip_runtime.h>

#define B_  4
#define S_  2048
#define D_  1024
#define H_  16
#define DK_ 64

typedef unsigned short ushort;
typedef __attribute__((ext_vector_type(8))) short short8;
typedef __attribute__((ext_vector_type(8))) unsigned short ushort8;
typedef __attribute__((ext_vector_type(4))) float f32x4;

// scores use exp2: fold 0.125 * log2(e) into Q at projection time
#define QSCALE 0.18033688011112042f

__device__ __forceinline__ ushort f2bf(float f) {  // RNE
    unsigned int u = __float_as_uint(f);
    u += 0x7fffu + ((u >> 16) & 1u);
    return (ushort)(u >> 16);
}
__device__ __forceinline__ ushort f2bf_hu(float f) {  // round-half-up, f >= 0
    return (ushort)((__float_as_uint(f) + 0x8000u) >> 16);
}

__device__ __forceinline__ void gl_lds16(const ushort* g, ushort* ldsbase) {
    __builtin_amdgcn_global_load_lds(
        (const __attribute__((address_space(1))) void*)g,
        (__attribute__((address_space(3))) void*)ldsbase, 16, 0, 0);
}

// ---------------------------------------------------------------------------
// Cast q,k,v + Wq,Wk,Wv,Wo to bf16 in one launch.
// ---------------------------------------------------------------------------
__global__ __launch_bounds__(256) void cast_all(
    const float* __restrict__ q, const float* __restrict__ k,
    const float* __restrict__ v, const float* __restrict__ Wq,
    const float* __restrict__ Wk, const float* __restrict__ Wv,
    const float* __restrict__ Wo, ushort* __restrict__ qkv_dst,
    ushort* __restrict__ w_dst) {
    const int bid = blockIdx.x;
    const float* src;
    ushort* dst;
    int lb;
    if (bid < 12288) {
        const int s = bid >> 12;
        lb = bid & 4095;
        src = (s == 0) ? q : (s == 1) ? k : v;
        dst = qkv_dst + (size_t)s * (B_ * S_ * D_);
    } else {
        const int wi = (bid - 12288) >> 9;
        lb = (bid - 12288) & 511;
        src = (wi == 0) ? Wq : (wi == 1) ? Wk : (wi == 2) ? Wv : Wo;
        dst = w_dst + (size_t)wi * (D_ * D_);
    }
    const int i = lb * 2048 + threadIdx.x * 8;
    const float4 a = *(const float4*)(src + i);
    const float4 b = *(const float4*)(src + i + 4);
    ushort8 r;
    r[0] = f2bf(a.x); r[1] = f2bf(a.y); r[2] = f2bf(a.z); r[3] = f2bf(a.w);
    r[4] = f2bf(b.x); r[5] = f2bf(b.y); r[6] = f2bf(b.z); r[7] = f2bf(b.w);
    *(ushort8*)(dst + i) = r;
}

// ---------------------------------------------------------------------------
// int32 mask -> 1 bit per element (bit i of word = k position). 2 MB total.
// ---------------------------------------------------------------------------
__global__ __launch_bounds__(256) void mask_bits_kernel(
    const int* __restrict__ m, unsigned long long* __restrict__ bits) {
    const size_t idx = (size_t)blockIdx.x * 256 + threadIdx.x;
    const unsigned long long bal = __ballot(m[idx] != 0);
    if ((threadIdx.x & 63) == 0) bits[idx >> 6] = bal;
}

// ---------------------------------------------------------------------------
// Fused Q/K/V projection (blockIdx.z selects). out = (A @ W^T + b)*scale,
// bf16 scatter to [B,H,S,DK] (uniform, coalesced 32B runs).
// ---------------------------------------------------------------------------
__global__ __launch_bounds__(256) void gemm_proj(
    const ushort* __restrict__ qb, const ushort* __restrict__ kb,
    const ushort* __restrict__ vb, const ushort* __restrict__ Wb,
    const float* __restrict__ bq, const float* __restrict__ bk,
    const float* __restrict__ bv, ushort* __restrict__ Qd,
    ushort* __restrict__ Kd, ushort* __restrict__ Vd) {
    const int z = blockIdx.z;
    const ushort* A  = (z == 0) ? qb : (z == 1) ? kb : vb;
    const ushort* Wm = Wb + (size_t)z * (D_ * D_);
    const float* bias = (z == 0) ? bq : (z == 1) ? bk : bv;
    ushort* outp = (z == 0) ? Qd : (z == 1) ? Kd : Vd;
    const float scale = (z == 0) ? QSCALE : 1.0f;

    __shared__ ushort As[128 * 32];
    __shared__ ushort Bs[128 * 32];
    const int t = threadIdx.x, w = t >> 6, lane = t & 63;
    const int ln15 = lane & 15, quad = lane >> 4;
    const int wr = w >> 1, wc = w & 1;
    const int n0 = blockIdx.x * 128, m0 = blockIdx.y * 128;
    const int srow = lane >> 2;
    const int sg = (lane & 3) * 8;

    f32x4 acc[4][4] = {};
    for (int k0 = 0; k0 < D_; k0 += 32) {
#pragma unroll
        for (int c = 0; c < 2; ++c) {
            const int cc = w * 2 + c;
            const int row = cc * 16 + srow;
            gl_lds16(A + (size_t)(m0 + row) * D_ + k0 + sg, As + cc * 512);
            gl_lds16(Wm + (size_t)(n0 + row) * D_ + k0 + sg, Bs + cc * 512);
        }
        __syncthreads();
        short8 af[4], bf[4];
#pragma unroll
        for (int i = 0; i < 4; ++i) {
            af[i] = *(const short8*)(As + (wr * 64 + i * 16 + ln15) * 32 + quad * 8);
            bf[i] = *(const short8*)(Bs + (wc * 64 + i * 16 + ln15) * 32 + quad * 8);
        }
#pragma unroll
        for (int mt = 0; mt < 4; ++mt)
#pragma unroll
            for (int nt = 0; nt < 4; ++nt)
                acc[mt][nt] = __builtin_amdgcn_mfma_f32_16x16x32_bf16(
                    af[mt], bf[nt], acc[mt][nt], 0, 0, 0);
        __syncthreads();
    }
#pragma unroll
    for (int mt = 0; mt < 4; ++mt) {
#pragma unroll
        for (int r = 0; r < 4; ++r) {
            const int row = m0 + wr * 64 + mt * 16 + quad * 4 + r;
            const int bb = row >> 11, s = row & (S_ - 1);
#pragma unroll
            for (int nt = 0; nt < 4; ++nt) {
                const int col = n0 + wc * 64 + nt * 16 + ln15;
                const float vv = (acc[mt][nt][r] + bias[col]) * scale;
                const int h = col >> 6, dk = col & 63;
                outp[((((size_t)bb * H_ + h) * S_ + s) << 6) + dk] = f2bf(vv);
            }
        }
    }
}

// ---------------------------------------------------------------------------
// V [bh][s][dk] -> V^T [bh][dk][s] with XOR-swizzled 8-key groups per 64-key
// window: physical group = logical ^ (dk&7). Matches attn's async staging.
// ---------------------------------------------------------------------------
__global__ __launch_bounds__(256) void vtrans(const ushort* __restrict__ Vs_,
                                              ushort* __restrict__ Vt_) {
    __shared__ ushort L[64 * 76];
    const int t = threadIdx.x;
    const int bh = blockIdx.y;
    const int s0 = blockIdx.x * 64;
    const ushort* src = Vs_ + (size_t)bh * S_ * DK_;
    ushort* dst = Vt_ + (size_t)bh * DK_ * S_;
    const int r = t >> 2, g = t & 3;
#pragma unroll
    for (int gg = 0; gg < 2; ++gg) {
        const int grp = g + gg * 4;
        const ushort8 v = *(const ushort8*)(src + (size_t)(s0 + r) * DK_ + grp * 8);
        *(ushort8*)(&L[r * 76 + grp * 8]) = v;
    }
    __syncthreads();
    const int dim = t >> 2;
#pragma unroll
    for (int gg = 0; gg < 2; ++gg) {
        const int sg = g + gg * 4;          // logical key-group
        ushort8 o;
#pragma unroll
        for (int j = 0; j < 8; ++j) o[j] = L[(sg * 8 + j) * 76 + dim];
        const int pg = sg ^ (dim & 7);      // physical (swizzled) slot
        *(ushort8*)(dst + (size_t)dim * S_ + s0 + pg * 8) = o;
    }
}

// ---------------------------------------------------------------------------
// Output projection: fp32 out = A @ W^T + b, flat [M,D]
// ---------------------------------------------------------------------------
__global__ __launch_bounds__(256) void gemm_out(const ushort* __restrict__ A,
                                                const ushort* __restrict__ Wm,
                                                const float* __restrict__ bias,
                                                float* __restrict__ out) {
    __shared__ ushort As[128 * 32];
    __shared__ ushort Bs[128 * 32];
    const int t = threadIdx.x, w = t >> 6, lane = t & 63;
    const int ln15 = lane & 15, quad = lane >> 4;
    const int wr = w >> 1, wc = w & 1;
    const int n0 = blockIdx.x * 128, m0 = blockIdx.y * 128;
    const int srow = lane >> 2;
    const int sg = (lane & 3) * 8;

    f32x4 acc[4][4] = {};
    for (int k0 = 0; k0 < D_; k0 += 32) {
#pragma unroll
        for (int c = 0; c < 2; ++c) {
            const int cc = w * 2 + c;
            const int row = cc * 16 + srow;
            gl_lds16(A + (size_t)(m0 + row) * D_ + k0 + sg, As + cc * 512);
            gl_lds16(Wm + (size_t)(n0 + row) * D_ + k0 + sg, Bs + cc * 512);
        }
        __syncthreads();
        short8 af[4], bf[4];
#pragma unroll
        for (int i = 0; i < 4; ++i) {
            af[i] = *(const short8*)(As + (wr * 64 + i * 16 + ln15) * 32 + quad * 8);
            bf[i] = *(const short8*)(Bs + (wc * 64 + i * 16 + ln15) * 32 + quad * 8);
        }
#pragma unroll
        for (int mt = 0; mt < 4; ++mt)
#pragma unroll
            for (int nt = 0; nt < 4; ++nt)
                acc[mt][nt] = __builtin_amdgcn_mfma_f32_16x16x32_bf16(
                    af[mt], bf[nt], acc[mt][nt], 0, 0, 0);
        __syncthreads();
    }
#pragma unroll
    for (int mt = 0; mt < 4; ++mt) {
#pragma unroll
        for (int r = 0; r < 4; ++r) {
            const int row = m0 + wr * 64 + mt * 16 + quad * 4 + r;
#pragma unroll
            for (int nt = 0; nt < 4; ++nt) {
                const int col = n0 + wc * 64 + nt * 16 + ln15;
                out[(size_t)row * D_ + col] = acc[mt][nt][r] + bias[col];
            }
        }
    }
}

// ---------------------------------------------------------------------------
// Flash attention. LDS = Ks dbuf 16K + Vt dbuf 16K + Ps 18K = 50K -> 3 blk/CU.
// Q frags in registers (loaded once per block). K AND V staged via async
// global_load_lds one tile ahead -> the only VMEM wait is the barrier's drain,
// which lands a full tile of compute after issue. Mask bits prefetched.
// ---------------------------------------------------------------------------
__global__ __launch_bounds__(256, 3) void attn_mfma(
    const ushort* __restrict__ Qd, const ushort* __restrict__ Kd,
    const ushort* __restrict__ Vtg, const unsigned long long* __restrict__ bits,
    ushort* __restrict__ ctx) {
    __shared__ ushort Ks[2][64 * 64];  // [key][dk], swizzled groups
    __shared__ ushort Vt[2][64 * 64];  // [dk][key], swizzled groups
    __shared__ ushort Ps[128 * 72];    // [q][key] A-layout, padded

    const int t = threadIdx.x, w = t >> 6, lane = t & 63;
    const int ln15 = lane & 15, quad = lane >> 4;
    const int lp = lane & 7, lr8 = lane >> 3;
    const int bh = blockIdx.y, b = bh >> 4, h = bh & 15;
    const int q0 = blockIdx.x * 128;

    const ushort* Qb = Qd + (size_t)bh * (S_ * DK_);
    const ushort* Kb = Kd + (size_t)bh * (S_ * DK_);
    const ushort* Vb = Vtg + (size_t)bh * (DK_ * S_);  // [dk][s] swizzled
    const unsigned long long* mbits = bits + (size_t)b * S_ * (S_ / 64);

    int moff[2][4];
#pragma unroll
    for (int mt = 0; mt < 2; ++mt)
#pragma unroll
        for (int r = 0; r < 4; ++r)
            moff[mt][r] = (q0 + w * 32 + mt * 16 + quad * 4 + r) * (S_ / 64);

    // Q fragments: loaded once, live in registers all kernel
    short8 aq[2][2];  // [ks][mt]
#pragma unroll
    for (int ks = 0; ks < 2; ++ks)
#pragma unroll
        for (int mt = 0; mt < 2; ++mt)
            aq[ks][mt] = *(const short8*)(
                Qb + (size_t)(q0 + w * 32 + mt * 16 + ln15) * DK_ + ks * 32 + quad * 8);

    // stage K/V tile kt into buffer p (async; drained by the NEXT barrier)
    auto stageKV = [&](int kt, int p) {
        const int k0 = kt * 64;
#pragma unroll
        for (int c = 0; c < 2; ++c) {
            const int cc = w * 2 + c;
            const int row = cc * 8 + lr8;  // K: key row; V: dk row
            gl_lds16(Kb + (size_t)(k0 + row) * DK_ + (lp ^ lr8) * 8, &Ks[p][cc * 512]);
            gl_lds16(Vb + (size_t)row * S_ + k0 + lp * 8, &Vt[p][cc * 512]);
        }
    };

    stageKV(0, 0);
    unsigned long long mw[2][4];
#pragma unroll
    for (int mt = 0; mt < 2; ++mt)
#pragma unroll
        for (int r = 0; r < 4; ++r) mw[mt][r] = mbits[moff[mt][r]];

    f32x4 O[2][4] = {};
    f32x4 lsum[2] = {};
    short8 vone;
#pragma unroll
    for (int j = 0; j < 8; ++j) vone[j] = (short)0x3F80;  // bf16(1.0)

    int p = 0;
    for (int kt = 0; kt < S_ / 64; ++kt) {
        __syncthreads();  // drains stageKV(kt); buffer p^1 now free
        if (kt < S_ / 64 - 1) stageKV(kt + 1, p ^ 1);

        // ---- S' = (Q*QSCALE) K^T
        f32x4 sc[2][4] = {};
#pragma unroll
        for (int ks = 0; ks < 2; ++ks) {
            short8 bk[4];
#pragma unroll
            for (int nt = 0; nt < 4; ++nt) {
                const int row = nt * 16 + ln15;
                bk[nt] = *(const short8*)(&Ks[p][row * 64 + ((ks * 4 + quad) ^ (row & 7)) * 8]);
            }
#pragma unroll
            for (int mt = 0; mt < 2; ++mt)
#pragma unroll
                for (int nt = 0; nt < 4; ++nt)
                    sc[mt][nt] = __builtin_amdgcn_mfma_f32_16x16x32_bf16(
                        aq[ks][mt], bk[nt], sc[mt][nt], 0, 0, 0);
        }

        // ---- P = maskbit ? exp2(S') : 0, to LDS in A-operand layout
#pragma unroll
        for (int mt = 0; mt < 2; ++mt) {
#pragma unroll
            for (int r = 0; r < 4; ++r) {
                const int prow = w * 32 + mt * 16 + quad * 4 + r;
                const unsigned long long mword = mw[mt][r];
#pragma unroll
                for (int nt = 0; nt < 4; ++nt) {
                    float pv = __builtin_amdgcn_exp2f(sc[mt][nt][r]);
                    pv = ((mword >> (ln15 + nt * 16)) & 1ull) ? pv : 0.0f;
                    Ps[prow * 72 + nt * 16 + ln15] = f2bf_hu(pv);
                }
            }
        }
        // prefetch mask for kt+1
        if (kt < S_ / 64 - 1) {
#pragma unroll
            for (int mt = 0; mt < 2; ++mt)
#pragma unroll
                for (int r = 0; r < 4; ++r)
                    mw[mt][r] = mbits[moff[mt][r] + kt + 1];
        }
        // Ps rows are wave-private; in-wave lgkmcnt ordering suffices

        // ---- O += P V^T ; lsum += P @ ones
#pragma unroll
        for (int ks = 0; ks < 2; ++ks) {
            short8 ap[2], bv4[4];
#pragma unroll
            for (int mt = 0; mt < 2; ++mt)
                ap[mt] = *(const short8*)(Ps + (w * 32 + mt * 16 + ln15) * 72 + ks * 32 + quad * 8);
#pragma unroll
            for (int nt = 0; nt < 4; ++nt) {
                const int dim = nt * 16 + ln15;
                bv4[nt] = *(const short8*)(&Vt[p][dim * 64 + ((ks * 4 + quad) ^ (dim & 7)) * 8]);
            }
#pragma unroll
            for (int mt = 0; mt < 2; ++mt) {
#pragma unroll
                for (int nt = 0; nt < 4; ++nt)
                    O[mt][nt] = __builtin_amdgcn_mfma_f32_16x16x32_bf16(
                        ap[mt], bv4[nt], O[mt][nt], 0, 0, 0);
                lsum[mt] = __builtin_amdgcn_mfma_f32_16x16x32_bf16(
                    ap[mt], vone, lsum[mt], 0, 0, 0);
            }
        }
        p ^= 1;
    }

    // finalize: ctx[b][s][h*64+dim] = O / lsum (bf16, feeds out-proj)
#pragma unroll
    for (int mt = 0; mt < 2; ++mt) {
#pragma unroll
        for (int r = 0; r < 4; ++r) {
            const int qg = q0 + w * 32 + mt * 16 + quad * 4 + r;
            const float inv = __builtin_amdgcn_rcpf(lsum[mt][r]);
#pragma unroll
            for (int nt = 0; nt < 4; ++nt) {
                const int dim = nt * 16 + ln15;
                ctx[((size_t)b * S_ + qg) * D_ + h * DK_ + dim] = f2bf(O[mt][nt][r] * inv);
            }
        }
    }
}

// ---------------------------------------------------------------------------
extern "C" void kernel_launch(void* const* d_in, const int* in_sizes, int n_in,
                              void* d_out, int out_size, void* d_ws, size_t ws_size,
                              hipStream_t stream) {
    (void)in_sizes; (void)n_in; (void)out_size; (void)ws_size;
    const float* query = (const float*)d_in[0];
    const float* key_  = (const float*)d_in[1];
    const float* value = (const float*)d_in[2];
    const int*   mask  = (const int*)d_in[3];
    const float* Wq = (const float*)d_in[4];
    const float* bq = (const float*)d_in[5];
    const float* Wk = (const float*)d_in[6];
    const float* bk = (const float*)d_in[7];
    const float* Wv = (const float*)d_in[8];
    const float* bv = (const float*)d_in[9];
    const float* Wo = (const float*)d_in[10];
    const float* bo = (const float*)d_in[11];
    float* out = (float*)d_out;

    const size_t nX = (size_t)B_ * S_ * D_;  // 8,388,608
    const size_t nW = (size_t)D_ * D_;       // 1,048,576
    ushort* qkv = (ushort*)d_ws;       // 3*nX bf16 (q,k,v casts)
    ushort* Wb  = qkv + 3 * nX;        // 4*nW bf16
    ushort* Qd  = Wb + 4 * nW;
    ushort* Kd  = Qd + nX;
    ushort* Vd  = Kd + nX;             // standard [B,H,S,DK]
    unsigned long long* bits = (unsigned long long*)(Vd + nX);  // 2 MB
    ushort* ctx = qkv;                 // q-cast region, dead after gemm_proj
    ushort* VtT = qkv + 2 * nX;        // v-cast region, dead after gemm_proj

    cast_all<<<14336, 256, 0, stream>>>(query, key_, value, Wq, Wk, Wv, Wo, qkv, Wb);
    mask_bits_kernel<<<B_ * S_ * S_ / 256, 256, 0, stream>>>(mask, bits);

    dim3 gp(D_ / 128, (B_ * S_) / 128, 3);  // (8, 64, 3)
    gemm_proj<<<gp, 256, 0, stream>>>(qkv, qkv + nX, qkv + 2 * nX, Wb,
                                      bq, bk, bv, Qd, Kd, Vd);

    dim3 gv(S_ / 64, B_ * H_);  // (32, 64)
    vtrans<<<gv, 256, 0, stream>>>(Vd, VtT);

    dim3 ga(S_ / 128, B_ * H_);  // (16, 64)
    attn_mfma<<<ga, 256, 0, stream>>>(Qd, Kd, VtT, bits, ctx);

    dim3 go(D_ / 128, (B_ * S_) / 128);  // (8, 64)
    gemm_out<<<go, 256, 0, stream>>>(ctx, Wb + 3 * nW, bo, out);
}